// Round 11
// baseline (257.132 us; speedup 1.0000x reference)
//
#include <hip/hip_runtime.h>
#include <hip/hip_bf16.h>

#define IN_F 8192
#define OUT_F 8192
#define SEQ 64
#define LORA_R 16

typedef __attribute__((ext_vector_type(4))) float f32x4;
typedef __attribute__((ext_vector_type(4))) int i32x4;
typedef __attribute__((ext_vector_type(4))) unsigned short u16x4;
typedef _Float16 f16x2 __attribute__((ext_vector_type(2)));
typedef _Float16 f16x8 __attribute__((ext_vector_type(8)));

// ---- prep (measured, R5/R8 verbatim): xb = fp16(x); t partials = x@A^T (K/4). ----
__global__ __launch_bounds__(256) void k_prep(
    const float* __restrict__ x, const float* __restrict__ A,
    unsigned short* __restrict__ xb, float* __restrict__ t) {
    __shared__ float part[64];
    const int s = blockIdx.x >> 2, p = blockIdx.x & 3;
    const int w = threadIdx.x >> 6, lane = threadIdx.x & 63;
    const int kbase = p * 2048 + w * 512;
    const float* xr = x + s * IN_F + kbase;

    f32x4 xv[2];
    #pragma unroll
    for (int j = 0; j < 2; ++j) {
        xv[j] = *(const f32x4*)(xr + j * 256 + lane * 4);
        u16x4 h;
        h[0] = __builtin_bit_cast(unsigned short, (_Float16)xv[j].x);
        h[1] = __builtin_bit_cast(unsigned short, (_Float16)xv[j].y);
        h[2] = __builtin_bit_cast(unsigned short, (_Float16)xv[j].z);
        h[3] = __builtin_bit_cast(unsigned short, (_Float16)xv[j].w);
        *(u16x4*)(xb + s * IN_F + kbase + j * 256 + lane * 4) = h;
    }

    float acc[LORA_R];
    #pragma unroll
    for (int r = 0; r < LORA_R; ++r) acc[r] = 0.f;
    #pragma unroll
    for (int r = 0; r < LORA_R; ++r) {
        const float* ar = A + r * IN_F + kbase;
        #pragma unroll
        for (int j = 0; j < 2; ++j) {
            f32x4 av = *(const f32x4*)(ar + j * 256 + lane * 4);
            acc[r] = fmaf(xv[j].x, av.x, acc[r]);
            acc[r] = fmaf(xv[j].y, av.y, acc[r]);
            acc[r] = fmaf(xv[j].z, av.z, acc[r]);
            acc[r] = fmaf(xv[j].w, av.w, acc[r]);
        }
    }
    #pragma unroll
    for (int r = 0; r < LORA_R; ++r) {
        float v = acc[r];
        #pragma unroll
        for (int off = 32; off; off >>= 1) v += __shfl_down(v, off, 64);
        if (lane == 0) part[w * 16 + r] = v;
    }
    __syncthreads();
    if (threadIdx.x < 16)
        t[s * 64 + p * 16 + threadIdx.x] = part[threadIdx.x] + part[16 + threadIdx.x] +
                                           part[32 + threadIdx.x] + part[48 + threadIdx.x];
}

// ---- main: 512 blocks (BN=16 n-tile, FULL K), 512 thr = 8 waves, 2 blocks/CU ----
// ZERO barriers in K-loop; NO LDS for W or x. Wave w owns k-slice w of each
// BK=256 chunk: per iter 1 W i32x4 + 4 x f16x8 per lane, all global->reg,
// 2-deep register double-buffer (A/B sets). Lanes q=0..3 cover 64 contiguous
// bytes per row -> fully-consumed cache lines for BOTH operands.
// W rows: exclusive per block (HBM stream). x: 1 MiB, L2-hot, shared.
// 16 independent waves/CU provide the latency hiding (m114 TLP mechanism).
// LDS 40000 B: scs[16][132]f16 (loop) | alias: accs[8][64*17] @0,
// tred[64][16] @34816, bs[16][17] @38912 (epilogue).
__global__ __launch_bounds__(512, 4) void k_main(
    const int* __restrict__ packed, const float* __restrict__ scales,
    const unsigned short* __restrict__ xb, const float* __restrict__ t,
    const float* __restrict__ B, float* __restrict__ out) {
    __shared__ char lds[40000];
    _Float16* scs = (_Float16*)lds;              // [16][132] f16 (loop phase)
    float* accs = (float*)lds;                   // [8][64*17] (epilogue alias)
    float* tred = (float*)(lds + 34816);         // [64][16]
    float* bs   = (float*)(lds + 38912);         // [16][17]

    const int tid = threadIdx.x;
    const int n0 = blockIdx.x * 16;
    const int w = tid >> 6, lane = tid & 63;
    const int q = lane >> 4, c16 = lane & 15;

    // ---- scales: 16 rows x 128, f32 -> f16, staged once ----
    if (tid < 256) {
        int row = tid >> 4, g = tid & 15;
        const float* sp = scales + (size_t)(n0 + row) * (IN_F / 64) + g * 8;
        f32x4 a = *(const f32x4*)sp;
        f32x4 b = *(const f32x4*)(sp + 4);
        u16x4 ha, hb;
        ha[0] = __builtin_bit_cast(unsigned short, (_Float16)a.x);
        ha[1] = __builtin_bit_cast(unsigned short, (_Float16)a.y);
        ha[2] = __builtin_bit_cast(unsigned short, (_Float16)a.z);
        ha[3] = __builtin_bit_cast(unsigned short, (_Float16)a.w);
        hb[0] = __builtin_bit_cast(unsigned short, (_Float16)b.x);
        hb[1] = __builtin_bit_cast(unsigned short, (_Float16)b.y);
        hb[2] = __builtin_bit_cast(unsigned short, (_Float16)b.z);
        hb[3] = __builtin_bit_cast(unsigned short, (_Float16)b.w);
        *(u16x4*)((unsigned short*)scs + row * 132 + g * 8)     = ha;
        *(u16x4*)((unsigned short*)scs + row * 132 + g * 8 + 4) = hb;
    }
    __syncthreads();

    // ---- per-lane streaming pointers ----
    // W: row n0+c16, slice w, quarter q -> ints (w*16 + q*4); +128 ints/iter
    const int* wp = packed + (size_t)(n0 + c16) * (IN_F / 2) + w * 16 + q * 4;
    // x: rows mt*16+c16, k = kt*256 + w*32 + q*8 halves
    const _Float16* xf0 = (const _Float16*)xb + (size_t)(c16)      * IN_F + w * 32 + q * 8;
    const _Float16* xf1 = (const _Float16*)xb + (size_t)(16 + c16) * IN_F + w * 32 + q * 8;
    const _Float16* xf2 = (const _Float16*)xb + (size_t)(32 + c16) * IN_F + w * 32 + q * 8;
    const _Float16* xf3 = (const _Float16*)xb + (size_t)(48 + c16) * IN_F + w * 32 + q * 8;
    const int sci = c16 * 132 + (w >> 1);        // + kt*4 per iter

    f32x4 acc[4];
    #pragma unroll
    for (int mt = 0; mt < 4; ++mt) acc[mt] = (f32x4){0.f, 0.f, 0.f, 0.f};

    const f16x2 c1032 = {(_Float16)1032.0f, (_Float16)1032.0f};

    // ---- register double-buffer (A/B sets), no barriers ----
    i32x4 pvA, pvB;
    f16x8 afA0, afA1, afA2, afA3, afB0, afB1, afB2, afB3;
    pvA = *(const i32x4*)wp;
    afA0 = *(const f16x8*)xf0; afA1 = *(const f16x8*)xf1;
    afA2 = *(const f16x8*)xf2; afA3 = *(const f16x8*)xf3;

    for (int kt = 0; kt < 32; kt += 2) {
        // prefetch kt+1 into B
        if (kt + 1 < 32) {
            const size_t wo = (size_t)(kt + 1) * 128, xo = (size_t)(kt + 1) * 256;
            pvB = *(const i32x4*)(wp + wo);
            afB0 = *(const f16x8*)(xf0 + xo); afB1 = *(const f16x8*)(xf1 + xo);
            afB2 = *(const f16x8*)(xf2 + xo); afB3 = *(const f16x8*)(xf3 + xo);
        }
        // compute kt from A
        {
            _Float16 sch = scs[sci + kt * 4];
            f16x2 sc2 = {sch, sch};
            f16x8 bf;
            #pragma unroll
            for (int m = 0; m < 4; ++m) {
                unsigned u = ((((unsigned)pvA[m] << 12) | (unsigned)pvA[m]) & 0x000F000Fu) | 0x64006400u;
                f16x2 h = __builtin_bit_cast(f16x2, u);
                h = (h - c1032) * sc2;       // exact (q-8)*scale
                bf[2 * m] = h.x; bf[2 * m + 1] = h.y;
            }
            acc[0] = __builtin_amdgcn_mfma_f32_16x16x32_f16(afA0, bf, acc[0], 0, 0, 0);
            acc[1] = __builtin_amdgcn_mfma_f32_16x16x32_f16(afA1, bf, acc[1], 0, 0, 0);
            acc[2] = __builtin_amdgcn_mfma_f32_16x16x32_f16(afA2, bf, acc[2], 0, 0, 0);
            acc[3] = __builtin_amdgcn_mfma_f32_16x16x32_f16(afA3, bf, acc[3], 0, 0, 0);
        }
        // prefetch kt+2 into A
        if (kt + 2 < 32) {
            const size_t wo = (size_t)(kt + 2) * 128, xo = (size_t)(kt + 2) * 256;
            pvA = *(const i32x4*)(wp + wo);
            afA0 = *(const f16x8*)(xf0 + xo); afA1 = *(const f16x8*)(xf1 + xo);
            afA2 = *(const f16x8*)(xf2 + xo); afA3 = *(const f16x8*)(xf3 + xo);
        }
        // compute kt+1 from B
        if (kt + 1 < 32) {
            _Float16 sch = scs[sci + (kt + 1) * 4];
            f16x2 sc2 = {sch, sch};
            f16x8 bf;
            #pragma unroll
            for (int m = 0; m < 4; ++m) {
                unsigned u = ((((unsigned)pvB[m] << 12) | (unsigned)pvB[m]) & 0x000F000Fu) | 0x64006400u;
                f16x2 h = __builtin_bit_cast(f16x2, u);
                h = (h - c1032) * sc2;
                bf[2 * m] = h.x; bf[2 * m + 1] = h.y;
            }
            acc[0] = __builtin_amdgcn_mfma_f32_16x16x32_f16(afB0, bf, acc[0], 0, 0, 0);
            acc[1] = __builtin_amdgcn_mfma_f32_16x16x32_f16(afB1, bf, acc[1], 0, 0, 0);
            acc[2] = __builtin_amdgcn_mfma_f32_16x16x32_f16(afB2, bf, acc[2], 0, 0, 0);
            acc[3] = __builtin_amdgcn_mfma_f32_16x16x32_f16(afB3, bf, acc[3], 0, 0, 0);
        }
    }

    __syncthreads();   // all waves done with scs before accs alias overwrite

    // ---- epilogue: 8-wave reduce + t reduce + LoRA, direct store ----
    float* myacc = accs + w * (64 * 17);
    #pragma unroll
    for (int mt = 0; mt < 4; ++mt)
        #pragma unroll
        for (int r = 0; r < 4; ++r)
            myacc[(mt * 16 + q * 4 + r) * 17 + c16] = acc[mt][r];
    #pragma unroll
    for (int jj = 0; jj < 2; ++jj) {
        int p2 = tid + jj * 512;                  // 1024 = 64 s x 16 r
        const float* tp = t + (p2 >> 4) * 64 + (p2 & 15);
        tred[p2] = tp[0] + tp[16] + tp[32] + tp[48];
    }
    if (tid < 256) {
        int row = tid >> 4, r = tid & 15;
        bs[row * 17 + r] = B[(size_t)(n0 + row) * LORA_R + r];
    }
    __syncthreads();

    #pragma unroll
    for (int j = 0; j < 2; ++j) {
        int p = tid + j * 512;                    // 1024 outputs: s 0..63, c 0..15
        int s = p >> 4, c = p & 15;
        const float* ap = accs + s * 17 + c;
        float v = 0.f;
        #pragma unroll
        for (int ww = 0; ww < 8; ++ww) v += ap[ww * (64 * 17)];
        const float* trow = tred + s * 16;
        const float* brow = bs + c * 17;
        float lr = 0.f;
        #pragma unroll
        for (int r = 0; r < 16; ++r) lr = fmaf(trow[r], brow[r], lr);
        out[(size_t)s * OUT_F + n0 + c] = v + 2.0f * lr;
    }
}

extern "C" void kernel_launch(void* const* d_in, const int* in_sizes, int n_in,
                              void* d_out, int out_size, void* d_ws, size_t ws_size,
                              hipStream_t stream) {
    const float* x      = (const float*)d_in[0];
    const int* packed   = (const int*)d_in[1];
    const float* scales = (const float*)d_in[2];
    const float* lora_A = (const float*)d_in[3];
    const float* lora_B = (const float*)d_in[4];
    float* out = (float*)d_out;

    unsigned short* xb = (unsigned short*)d_ws;                    // 1 MiB fp16 x
    float* t = (float*)((char*)d_ws + (size_t)SEQ * IN_F * 2);     // 16 KiB partials

    k_prep<<<256, 256, 0, stream>>>(x, lora_A, xb, t);
    k_main<<<512, 512, 0, stream>>>(packed, scales, xb, t, lora_B, out);
}

// Round 13
// 211.040 us; speedup vs baseline: 1.2184x; 1.2184x over previous
//
#include <hip/hip_runtime.h>
#include <hip/hip_bf16.h>

#define IN_F 8192
#define OUT_F 8192
#define SEQ 64
#define LORA_R 16

typedef __attribute__((ext_vector_type(4))) float f32x4;
typedef __attribute__((ext_vector_type(4))) int i32x4;
typedef __attribute__((ext_vector_type(4))) unsigned short u16x4;
typedef _Float16 f16x2 __attribute__((ext_vector_type(2)));
typedef _Float16 f16x8 __attribute__((ext_vector_type(8)));

typedef __attribute__((address_space(3))) unsigned int lds_u32;
typedef const __attribute__((address_space(1))) unsigned int glb_u32;

__device__ __forceinline__ void gl_lds16(const void* g, void* l) {
    __builtin_amdgcn_global_load_lds((glb_u32*)g, (lds_u32*)l, 16, 0, 0);
}

#define VMCNT(n) asm volatile("s_waitcnt vmcnt(" #n ")" ::: "memory")

// ---- prep (R5 verbatim, measured): xb = fp16(x); t partials = x@A^T (K/4). ----
__global__ __launch_bounds__(256) void k_prep(
    const float* __restrict__ x, const float* __restrict__ A,
    unsigned short* __restrict__ xb, float* __restrict__ t) {
    __shared__ float part[64];
    const int s = blockIdx.x >> 2, p = blockIdx.x & 3;
    const int w = threadIdx.x >> 6, lane = threadIdx.x & 63;
    const int kbase = p * 2048 + w * 512;
    const float* xr = x + s * IN_F + kbase;

    f32x4 xv[2];
    #pragma unroll
    for (int j = 0; j < 2; ++j) {
        xv[j] = *(const f32x4*)(xr + j * 256 + lane * 4);
        u16x4 h;
        h[0] = __builtin_bit_cast(unsigned short, (_Float16)xv[j].x);
        h[1] = __builtin_bit_cast(unsigned short, (_Float16)xv[j].y);
        h[2] = __builtin_bit_cast(unsigned short, (_Float16)xv[j].z);
        h[3] = __builtin_bit_cast(unsigned short, (_Float16)xv[j].w);
        *(u16x4*)(xb + s * IN_F + kbase + j * 256 + lane * 4) = h;
    }

    float acc[LORA_R];
    #pragma unroll
    for (int r = 0; r < LORA_R; ++r) acc[r] = 0.f;
    #pragma unroll
    for (int r = 0; r < LORA_R; ++r) {
        const float* ar = A + r * IN_F + kbase;
        #pragma unroll
        for (int j = 0; j < 2; ++j) {
            f32x4 av = *(const f32x4*)(ar + j * 256 + lane * 4);
            acc[r] = fmaf(xv[j].x, av.x, acc[r]);
            acc[r] = fmaf(xv[j].y, av.y, acc[r]);
            acc[r] = fmaf(xv[j].z, av.z, acc[r]);
            acc[r] = fmaf(xv[j].w, av.w, acc[r]);
        }
    }
    #pragma unroll
    for (int r = 0; r < LORA_R; ++r) {
        float v = acc[r];
        #pragma unroll
        for (int off = 32; off; off >>= 1) v += __shfl_down(v, off, 64);
        if (lane == 0) part[w * 16 + r] = v;
    }
    __syncthreads();
    if (threadIdx.x < 16)
        t[s * 64 + p * 16 + threadIdx.x] = part[threadIdx.x] + part[16 + threadIdx.x] +
                                           part[32 + threadIdx.x] + part[48 + threadIdx.x];
}

// ---- main (R8 verbatim, measured best 210.3): 256 blocks, 512 thr, BK=256 ----
// 32 iterations. Chunks: W 16KB (32rows x 128 ints), x 32KB (64rows x 256 f16).
// 3 buffers each, issue-ahead 2 -> ~96KB/CU in flight; uniform vmcnt(6), never
// drained mid-loop (T4). Coalesced global_load_lds staging (the decisive 2x vs
// per-lane global reads, R10/R11 evidence). Scales f16 in LDS.
// Per wave/iter: 2 k-slices {wkk, wkk+4} x 4 mt = 8 MFMA.
// XOR swizzle (16B slot ^= row&7) via pre-XOR'd global src; swizzled LDS reads.
// LDS (155904 B): xs 3x32768 | wt 3x16384 @98304 | scs [32][132] f16 @147456
// epilogue alias: accs[8][64*17] f32 @0; tred[64][16] f32 @36864.
__global__ __launch_bounds__(512, 2) void k_main(
    const int* __restrict__ packed, const float* __restrict__ scales,
    const unsigned short* __restrict__ xb, const float* __restrict__ t,
    const float* __restrict__ B, float* __restrict__ out) {
    __shared__ char lds[155904];
    _Float16* xs = (_Float16*)lds;               // 3 x 16384 f16
    int* wt = (int*)(lds + 98304);               // 3 x 4096 int
    _Float16* scs = (_Float16*)(lds + 147456);   // 32*132 f16
    float* accs = (float*)lds;
    float* tred = (float*)(lds + 36864);

    const int tid = threadIdx.x;
    const int n0 = blockIdx.x * 32;
    const int w = tid >> 6, lane = tid & 63;
    const int nh = w >> 2, wkk = w & 3;
    const int q = lane >> 4, c16 = lane & 15;
    const int l5 = lane >> 5, l31 = lane & 31;

    // ---- scales staging: f32 -> f16 once ----
    {
        int row = tid >> 4, g = tid & 15;
        const float* sp = scales + (n0 + row) * (IN_F / 64);
        f32x4 a = *(const f32x4*)(sp + g * 4);
        f32x4 b = *(const f32x4*)(sp + 64 + g * 4);
        u16x4 ha, hb;
        ha[0] = __builtin_bit_cast(unsigned short, (_Float16)a.x);
        ha[1] = __builtin_bit_cast(unsigned short, (_Float16)a.y);
        ha[2] = __builtin_bit_cast(unsigned short, (_Float16)a.z);
        ha[3] = __builtin_bit_cast(unsigned short, (_Float16)a.w);
        hb[0] = __builtin_bit_cast(unsigned short, (_Float16)b.x);
        hb[1] = __builtin_bit_cast(unsigned short, (_Float16)b.y);
        hb[2] = __builtin_bit_cast(unsigned short, (_Float16)b.z);
        hb[3] = __builtin_bit_cast(unsigned short, (_Float16)b.w);
        *(u16x4*)((unsigned short*)scs + row * 132 + g * 4) = ha;
        *(u16x4*)((unsigned short*)scs + row * 132 + 64 + g * 4) = hb;
    }

    // ---- per-lane staging sources, 16B slot pre-XOR'd with (row&7) ----
    // x: 4 gl_lds/wave, rows 8w+2j+l5 (2 rows per gl_lds)
    const unsigned short* xg[4];
    #pragma unroll
    for (int j = 0; j < 4; ++j) {
        int row = 8 * w + 2 * j + l5;
        xg[j] = xb + (size_t)row * IN_F + ((l31 ^ (row & 7)) << 3);
    }
    _Float16* xd = xs + w * 2048;                // + buf*16384 + j*512
    // W: 2 gl_lds/wave, rows 4w+l5 and 4w+2+l5
    const int wr0 = 4 * w + l5, wr1 = wr0 + 2;
    const int* wg0 = packed + (size_t)(n0 + wr0) * (IN_F / 2) + ((l31 ^ (wr0 & 7)) << 2);
    const int* wg1 = packed + (size_t)(n0 + wr1) * (IN_F / 2) + ((l31 ^ (wr1 & 7)) << 2);
    int* wd = wt + w * 512;                      // + buf*4096 (+256 for 2nd)

    // ---- loop-invariant swizzled read offsets ----
    const int row_w = nh * 16 + c16, r7 = c16 & 7;
    const int pvo0 = row_w * 128 + ((4 * wkk + q) ^ r7) * 4;
    const int pvo1 = row_w * 128 + ((4 * (wkk + 4) + q) ^ r7) * 4;
    int afo0[4], afo1[4];
    #pragma unroll
    for (int mt = 0; mt < 4; ++mt) {
        afo0[mt] = (mt * 16 + c16) * 256 + ((4 * wkk + q) ^ r7) * 8;
        afo1[mt] = (mt * 16 + c16) * 256 + ((4 * (wkk + 4) + q) ^ r7) * 8;
    }
    const int scso = row_w * 132 + (wkk >> 1);

    f32x4 acc[4];
    #pragma unroll
    for (int mt = 0; mt < 4; ++mt) acc[mt] = (f32x4){0.f, 0.f, 0.f, 0.f};

    // ---- prologue: stage chunks 0,1 (x first, then W — W(c) is gating op) ----
    #pragma unroll
    for (int c = 0; c < 2; ++c) {
        #pragma unroll
        for (int j = 0; j < 4; ++j)
            gl_lds16(xg[j] + (size_t)c * 256, xd + c * 16384 + j * 512);
        gl_lds16(wg0 + (size_t)c * 128, wd + c * 4096);
        gl_lds16(wg1 + (size_t)c * 128, wd + c * 4096 + 256);
    }
    asm volatile("s_waitcnt lgkmcnt(0)" ::: "memory");   // scs visible
    __builtin_amdgcn_s_barrier();

    const f16x2 c1032 = {(_Float16)1032.0f, (_Float16)1032.0f};

    for (int kt = 0; kt < 32; ++kt) {
        // chunk kt resident (6 newer ops may fly); barrier; issue kt+2
        if (kt < 31) VMCNT(6);
        else         VMCNT(0);
        __builtin_amdgcn_s_barrier();
        __builtin_amdgcn_sched_barrier(0);
        const int cb = kt % 3;
        if (kt <= 29) {
            const int nb = (kt + 2) % 3;
            const size_t xo = (size_t)(kt + 2) * 256;
            const size_t wo = (size_t)(kt + 2) * 128;
            #pragma unroll
            for (int j = 0; j < 4; ++j)
                gl_lds16(xg[j] + xo, xd + nb * 16384 + j * 512);
            gl_lds16(wg0 + wo, wd + nb * 4096);
            gl_lds16(wg1 + wo, wd + nb * 4096 + 256);
        }
        // compute: 2 k-slices from buffer cb
        i32x4 pv0 = *(const i32x4*)(wt + cb * 4096 + pvo0);
        i32x4 pv1 = *(const i32x4*)(wt + cb * 4096 + pvo1);
        _Float16 s0 = scs[scso + kt * 4];
        _Float16 s1 = scs[scso + kt * 4 + 2];
        f16x2 sc0 = {s0, s0}, sc1 = {s1, s1};
        f16x8 bf0, bf1;
        #pragma unroll
        for (int m = 0; m < 4; ++m) {
            unsigned u0 = ((((unsigned)pv0[m] << 12) | (unsigned)pv0[m]) & 0x000F000Fu) | 0x64006400u;
            unsigned u1 = ((((unsigned)pv1[m] << 12) | (unsigned)pv1[m]) & 0x000F000Fu) | 0x64006400u;
            f16x2 h0 = __builtin_bit_cast(f16x2, u0);
            f16x2 h1 = __builtin_bit_cast(f16x2, u1);
            h0 = (h0 - c1032) * sc0;         // exact (q-8)*scale
            h1 = (h1 - c1032) * sc1;
            bf0[2 * m] = h0.x; bf0[2 * m + 1] = h0.y;
            bf1[2 * m] = h1.x; bf1[2 * m + 1] = h1.y;
        }
        const _Float16* xbase = xs + cb * 16384;
        #pragma unroll
        for (int mt = 0; mt < 4; ++mt) {
            f16x8 af = *(const f16x8*)(xbase + afo0[mt]);
            acc[mt] = __builtin_amdgcn_mfma_f32_16x16x32_f16(af, bf0, acc[mt], 0, 0, 0);
        }
        #pragma unroll
        for (int mt = 0; mt < 4; ++mt) {
            f16x8 af = *(const f16x8*)(xbase + afo1[mt]);
            acc[mt] = __builtin_amdgcn_mfma_f32_16x16x32_f16(af, bf1, acc[mt], 0, 0, 0);
        }
    }
    __syncthreads();   // all waves done with xs/wt/scs before alias overwrite

    // ---- epilogue: partials -> LDS, t reduce, LoRA, store ----
    float* myacc = accs + w * (64 * 17);
    #pragma unroll
    for (int mt = 0; mt < 4; ++mt)
        #pragma unroll
        for (int r = 0; r < 4; ++r)
            myacc[(mt * 16 + q * 4 + r) * 17 + c16] = acc[mt][r];
    #pragma unroll
    for (int jj = 0; jj < 2; ++jj) {
        int p2 = tid + jj * 512;                  // 1024 = 64 s x 16 r
        const float* tp = t + (p2 >> 4) * 64 + (p2 & 15);
        tred[p2] = tp[0] + tp[16] + tp[32] + tp[48];
    }
    __syncthreads();

    #pragma unroll
    for (int j = 0; j < 4; ++j) {
        int p = tid + j * 512;                    // 2048 outputs: s in 0..63, c in 0..31
        int s = p >> 5, c = p & 31;
        const float* ab = accs + (c >> 4) * 4 * (64 * 17) + s * 17 + (c & 15);
        float v = ab[0] + ab[64 * 17] + ab[2 * 64 * 17] + ab[3 * 64 * 17];
        const float* trow = tred + s * 16;
        const float* bp = B + (n0 + c) * LORA_R;
        f32x4 t0 = *(const f32x4*)trow,        t1 = *(const f32x4*)(trow + 4);
        f32x4 t2 = *(const f32x4*)(trow + 8),  t3 = *(const f32x4*)(trow + 12);
        f32x4 b0 = *(const f32x4*)bp,       b1 = *(const f32x4*)(bp + 4);
        f32x4 b2 = *(const f32x4*)(bp + 8), b3 = *(const f32x4*)(bp + 12);
        float lr = t0.x * b0.x + t0.y * b0.y + t0.z * b0.z + t0.w * b0.w
                 + t1.x * b1.x + t1.y * b1.y + t1.z * b1.z + t1.w * b1.w
                 + t2.x * b2.x + t2.y * b2.y + t2.z * b2.z + t2.w * b2.w
                 + t3.x * b3.x + t3.y * b3.y + t3.z * b3.z + t3.w * b3.w;
        v += 2.0f * lr;
        out[s * OUT_F + n0 + c] = v;
    }
}

extern "C" void kernel_launch(void* const* d_in, const int* in_sizes, int n_in,
                              void* d_out, int out_size, void* d_ws, size_t ws_size,
                              hipStream_t stream) {
    const float* x      = (const float*)d_in[0];
    const int* packed   = (const int*)d_in[1];
    const float* scales = (const float*)d_in[2];
    const float* lora_A = (const float*)d_in[3];
    const float* lora_B = (const float*)d_in[4];
    float* out = (float*)d_out;

    unsigned short* xb = (unsigned short*)d_ws;                    // 1 MiB fp16 x
    float* t = (float*)((char*)d_ws + (size_t)SEQ * IN_F * 2);     // 16 KiB partials

    k_prep<<<256, 256, 0, stream>>>(x, lora_A, xb, t);
    k_main<<<256, 512, 0, stream>>>(packed, scales, xb, t, lora_B, out);
}

// Round 18
// 210.082 us; speedup vs baseline: 1.2240x; 1.0046x over previous
//
#include <hip/hip_runtime.h>
#include <hip/hip_bf16.h>

#define IN_F 8192
#define OUT_F 8192
#define SEQ 64
#define LORA_R 16

typedef __attribute__((ext_vector_type(4))) float f32x4;
typedef __attribute__((ext_vector_type(4))) int i32x4;
typedef __attribute__((ext_vector_type(4))) unsigned short u16x4;
typedef _Float16 f16x2 __attribute__((ext_vector_type(2)));
typedef _Float16 f16x8 __attribute__((ext_vector_type(8)));

typedef __attribute__((address_space(3))) unsigned int lds_u32;
typedef const __attribute__((address_space(1))) unsigned int glb_u32;

__device__ __forceinline__ void gl_lds16(const void* g, void* l) {
    __builtin_amdgcn_global_load_lds((glb_u32*)g, (lds_u32*)l, 16, 0, 0);
}

#define VMCNT(n) asm volatile("s_waitcnt vmcnt(" #n ")" ::: "memory")

// ---- prep (R5 verbatim, measured): xb = fp16(x); t partials = x@A^T (K/4). ----
__global__ __launch_bounds__(256) void k_prep(
    const float* __restrict__ x, const float* __restrict__ A,
    unsigned short* __restrict__ xb, float* __restrict__ t) {
    __shared__ float part[64];
    const int s = blockIdx.x >> 2, p = blockIdx.x & 3;
    const int w = threadIdx.x >> 6, lane = threadIdx.x & 63;
    const int kbase = p * 2048 + w * 512;
    const float* xr = x + s * IN_F + kbase;

    f32x4 xv[2];
    #pragma unroll
    for (int j = 0; j < 2; ++j) {
        xv[j] = *(const f32x4*)(xr + j * 256 + lane * 4);
        u16x4 h;
        h[0] = __builtin_bit_cast(unsigned short, (_Float16)xv[j].x);
        h[1] = __builtin_bit_cast(unsigned short, (_Float16)xv[j].y);
        h[2] = __builtin_bit_cast(unsigned short, (_Float16)xv[j].z);
        h[3] = __builtin_bit_cast(unsigned short, (_Float16)xv[j].w);
        *(u16x4*)(xb + s * IN_F + kbase + j * 256 + lane * 4) = h;
    }

    float acc[LORA_R];
    #pragma unroll
    for (int r = 0; r < LORA_R; ++r) acc[r] = 0.f;
    #pragma unroll
    for (int r = 0; r < LORA_R; ++r) {
        const float* ar = A + r * IN_F + kbase;
        #pragma unroll
        for (int j = 0; j < 2; ++j) {
            f32x4 av = *(const f32x4*)(ar + j * 256 + lane * 4);
            acc[r] = fmaf(xv[j].x, av.x, acc[r]);
            acc[r] = fmaf(xv[j].y, av.y, acc[r]);
            acc[r] = fmaf(xv[j].z, av.z, acc[r]);
            acc[r] = fmaf(xv[j].w, av.w, acc[r]);
        }
    }
    #pragma unroll
    for (int r = 0; r < LORA_R; ++r) {
        float v = acc[r];
        #pragma unroll
        for (int off = 32; off; off >>= 1) v += __shfl_down(v, off, 64);
        if (lane == 0) part[w * 16 + r] = v;
    }
    __syncthreads();
    if (threadIdx.x < 16)
        t[s * 64 + p * 16 + threadIdx.x] = part[threadIdx.x] + part[16 + threadIdx.x] +
                                           part[32 + threadIdx.x] + part[48 + threadIdx.x];
}

// ---- main (R8 verbatim, measured best 210.3/211.0): 256 blocks, 512 thr, BK=256 ----
// 32 iterations. Chunks: W 16KB (32rows x 128 ints), x 32KB (64rows x 256 f16).
// 3 buffers each, issue-ahead 2 -> ~96KB/CU in flight; uniform vmcnt(6), never
// drained mid-loop (T4). Coalesced global_load_lds staging (the decisive 2x vs
// per-lane global reads, R10/R11 evidence). Scales f16 in LDS.
// Per wave/iter: 2 k-slices {wkk, wkk+4} x 4 mt = 8 MFMA.
// XOR swizzle (16B slot ^= row&7) via pre-XOR'd global src; swizzled LDS reads.
// LDS (155904 B): xs 3x32768 | wt 3x16384 @98304 | scs [32][132] f16 @147456
// epilogue alias: accs[8][64*17] f32 @0; tred[64][16] f32 @36864.
__global__ __launch_bounds__(512, 2) void k_main(
    const int* __restrict__ packed, const float* __restrict__ scales,
    const unsigned short* __restrict__ xb, const float* __restrict__ t,
    const float* __restrict__ B, float* __restrict__ out) {
    __shared__ char lds[155904];
    _Float16* xs = (_Float16*)lds;               // 3 x 16384 f16
    int* wt = (int*)(lds + 98304);               // 3 x 4096 int
    _Float16* scs = (_Float16*)(lds + 147456);   // 32*132 f16
    float* accs = (float*)lds;
    float* tred = (float*)(lds + 36864);

    const int tid = threadIdx.x;
    const int n0 = blockIdx.x * 32;
    const int w = tid >> 6, lane = tid & 63;
    const int nh = w >> 2, wkk = w & 3;
    const int q = lane >> 4, c16 = lane & 15;
    const int l5 = lane >> 5, l31 = lane & 31;

    // ---- scales staging: f32 -> f16 once ----
    {
        int row = tid >> 4, g = tid & 15;
        const float* sp = scales + (n0 + row) * (IN_F / 64);
        f32x4 a = *(const f32x4*)(sp + g * 4);
        f32x4 b = *(const f32x4*)(sp + 64 + g * 4);
        u16x4 ha, hb;
        ha[0] = __builtin_bit_cast(unsigned short, (_Float16)a.x);
        ha[1] = __builtin_bit_cast(unsigned short, (_Float16)a.y);
        ha[2] = __builtin_bit_cast(unsigned short, (_Float16)a.z);
        ha[3] = __builtin_bit_cast(unsigned short, (_Float16)a.w);
        hb[0] = __builtin_bit_cast(unsigned short, (_Float16)b.x);
        hb[1] = __builtin_bit_cast(unsigned short, (_Float16)b.y);
        hb[2] = __builtin_bit_cast(unsigned short, (_Float16)b.z);
        hb[3] = __builtin_bit_cast(unsigned short, (_Float16)b.w);
        *(u16x4*)((unsigned short*)scs + row * 132 + g * 4) = ha;
        *(u16x4*)((unsigned short*)scs + row * 132 + 64 + g * 4) = hb;
    }

    // ---- per-lane staging sources, 16B slot pre-XOR'd with (row&7) ----
    // x: 4 gl_lds/wave, rows 8w+2j+l5 (2 rows per gl_lds)
    const unsigned short* xg[4];
    #pragma unroll
    for (int j = 0; j < 4; ++j) {
        int row = 8 * w + 2 * j + l5;
        xg[j] = xb + (size_t)row * IN_F + ((l31 ^ (row & 7)) << 3);
    }
    _Float16* xd = xs + w * 2048;                // + buf*16384 + j*512
    // W: 2 gl_lds/wave, rows 4w+l5 and 4w+2+l5
    const int wr0 = 4 * w + l5, wr1 = wr0 + 2;
    const int* wg0 = packed + (size_t)(n0 + wr0) * (IN_F / 2) + ((l31 ^ (wr0 & 7)) << 2);
    const int* wg1 = packed + (size_t)(n0 + wr1) * (IN_F / 2) + ((l31 ^ (wr1 & 7)) << 2);
    int* wd = wt + w * 512;                      // + buf*4096 (+256 for 2nd)

    // ---- loop-invariant swizzled read offsets ----
    const int row_w = nh * 16 + c16, r7 = c16 & 7;
    const int pvo0 = row_w * 128 + ((4 * wkk + q) ^ r7) * 4;
    const int pvo1 = row_w * 128 + ((4 * (wkk + 4) + q) ^ r7) * 4;
    int afo0[4], afo1[4];
    #pragma unroll
    for (int mt = 0; mt < 4; ++mt) {
        afo0[mt] = (mt * 16 + c16) * 256 + ((4 * wkk + q) ^ r7) * 8;
        afo1[mt] = (mt * 16 + c16) * 256 + ((4 * (wkk + 4) + q) ^ r7) * 8;
    }
    const int scso = row_w * 132 + (wkk >> 1);

    f32x4 acc[4];
    #pragma unroll
    for (int mt = 0; mt < 4; ++mt) acc[mt] = (f32x4){0.f, 0.f, 0.f, 0.f};

    // ---- prologue: stage chunks 0,1 (x first, then W — W(c) is gating op) ----
    #pragma unroll
    for (int c = 0; c < 2; ++c) {
        #pragma unroll
        for (int j = 0; j < 4; ++j)
            gl_lds16(xg[j] + (size_t)c * 256, xd + c * 16384 + j * 512);
        gl_lds16(wg0 + (size_t)c * 128, wd + c * 4096);
        gl_lds16(wg1 + (size_t)c * 128, wd + c * 4096 + 256);
    }
    asm volatile("s_waitcnt lgkmcnt(0)" ::: "memory");   // scs visible
    __builtin_amdgcn_s_barrier();

    const f16x2 c1032 = {(_Float16)1032.0f, (_Float16)1032.0f};

    for (int kt = 0; kt < 32; ++kt) {
        // chunk kt resident (6 newer ops may fly); barrier; issue kt+2
        if (kt < 31) VMCNT(6);
        else         VMCNT(0);
        __builtin_amdgcn_s_barrier();
        __builtin_amdgcn_sched_barrier(0);
        const int cb = kt % 3;
        if (kt <= 29) {
            const int nb = (kt + 2) % 3;
            const size_t xo = (size_t)(kt + 2) * 256;
            const size_t wo = (size_t)(kt + 2) * 128;
            #pragma unroll
            for (int j = 0; j < 4; ++j)
                gl_lds16(xg[j] + xo, xd + nb * 16384 + j * 512);
            gl_lds16(wg0 + wo, wd + nb * 4096);
            gl_lds16(wg1 + wo, wd + nb * 4096 + 256);
        }
        // compute: 2 k-slices from buffer cb
        i32x4 pv0 = *(const i32x4*)(wt + cb * 4096 + pvo0);
        i32x4 pv1 = *(const i32x4*)(wt + cb * 4096 + pvo1);
        _Float16 s0 = scs[scso + kt * 4];
        _Float16 s1 = scs[scso + kt * 4 + 2];
        f16x2 sc0 = {s0, s0}, sc1 = {s1, s1};
        f16x8 bf0, bf1;
        #pragma unroll
        for (int m = 0; m < 4; ++m) {
            unsigned u0 = ((((unsigned)pv0[m] << 12) | (unsigned)pv0[m]) & 0x000F000Fu) | 0x64006400u;
            unsigned u1 = ((((unsigned)pv1[m] << 12) | (unsigned)pv1[m]) & 0x000F000Fu) | 0x64006400u;
            f16x2 h0 = __builtin_bit_cast(f16x2, u0);
            f16x2 h1 = __builtin_bit_cast(f16x2, u1);
            h0 = (h0 - c1032) * sc0;         // exact (q-8)*scale
            h1 = (h1 - c1032) * sc1;
            bf0[2 * m] = h0.x; bf0[2 * m + 1] = h0.y;
            bf1[2 * m] = h1.x; bf1[2 * m + 1] = h1.y;
        }
        const _Float16* xbase = xs + cb * 16384;
        #pragma unroll
        for (int mt = 0; mt < 4; ++mt) {
            f16x8 af = *(const f16x8*)(xbase + afo0[mt]);
            acc[mt] = __builtin_amdgcn_mfma_f32_16x16x32_f16(af, bf0, acc[mt], 0, 0, 0);
        }
        #pragma unroll
        for (int mt = 0; mt < 4; ++mt) {
            f16x8 af = *(const f16x8*)(xbase + afo1[mt]);
            acc[mt] = __builtin_amdgcn_mfma_f32_16x16x32_f16(af, bf1, acc[mt], 0, 0, 0);
        }
    }
    __syncthreads();   // all waves done with xs/wt/scs before alias overwrite

    // ---- epilogue: partials -> LDS, t reduce, LoRA, store ----
    float* myacc = accs + w * (64 * 17);
    #pragma unroll
    for (int mt = 0; mt < 4; ++mt)
        #pragma unroll
        for (int r = 0; r < 4; ++r)
            myacc[(mt * 16 + q * 4 + r) * 17 + c16] = acc[mt][r];
    #pragma unroll
    for (int jj = 0; jj < 2; ++jj) {
        int p2 = tid + jj * 512;                  // 1024 = 64 s x 16 r
        const float* tp = t + (p2 >> 4) * 64 + (p2 & 15);
        tred[p2] = tp[0] + tp[16] + tp[32] + tp[48];
    }
    __syncthreads();

    #pragma unroll
    for (int j = 0; j < 4; ++j) {
        int p = tid + j * 512;                    // 2048 outputs: s in 0..63, c in 0..31
        int s = p >> 5, c = p & 31;
        const float* ab = accs + (c >> 4) * 4 * (64 * 17) + s * 17 + (c & 15);
        float v = ab[0] + ab[64 * 17] + ab[2 * 64 * 17] + ab[3 * 64 * 17];
        const float* trow = tred + s * 16;
        const float* bp = B + (n0 + c) * LORA_R;
        f32x4 t0 = *(const f32x4*)trow,        t1 = *(const f32x4*)(trow + 4);
        f32x4 t2 = *(const f32x4*)(trow + 8),  t3 = *(const f32x4*)(trow + 12);
        f32x4 b0 = *(const f32x4*)bp,       b1 = *(const f32x4*)(bp + 4);
        f32x4 b2 = *(const f32x4*)(bp + 8), b3 = *(const f32x4*)(bp + 12);
        float lr = t0.x * b0.x + t0.y * b0.y + t0.z * b0.z + t0.w * b0.w
                 + t1.x * b1.x + t1.y * b1.y + t1.z * b1.z + t1.w * b1.w
                 + t2.x * b2.x + t2.y * b2.y + t2.z * b2.z + t2.w * b2.w
                 + t3.x * b3.x + t3.y * b3.y + t3.z * b3.z + t3.w * b3.w;
        v += 2.0f * lr;
        out[s * OUT_F + n0 + c] = v;
    }
}

extern "C" void kernel_launch(void* const* d_in, const int* in_sizes, int n_in,
                              void* d_out, int out_size, void* d_ws, size_t ws_size,
                              hipStream_t stream) {
    const float* x      = (const float*)d_in[0];
    const int* packed   = (const int*)d_in[1];
    const float* scales = (const float*)d_in[2];
    const float* lora_A = (const float*)d_in[3];
    const float* lora_B = (const float*)d_in[4];
    float* out = (float*)d_out;

    unsigned short* xb = (unsigned short*)d_ws;                    // 1 MiB fp16 x
    float* t = (float*)((char*)d_ws + (size_t)SEQ * IN_F * 2);     // 16 KiB partials

    k_prep<<<256, 256, 0, stream>>>(x, lora_A, xb, t);
    k_main<<<256, 512, 0, stream>>>(packed, scales, xb, t, lora_B, out);
}